// Round 3
// baseline (134.137 us; speedup 1.0000x reference)
//
#include <hip/hip_runtime.h>

// ---- compile-time physics constants (computed in double, cast to float) ----
constexpr double PI_D         = 3.14159265358979323846;
constexpr double WAVELENGTH_D = 12.398 / 11.3;
constexpr double K_D          = 2.0 * PI_D / WAVELENGTH_D;
constexpr double PIXELSIZE_D  = 5.5e-05 * 2.0;
constexpr double DISTANCE_D   = 0.85;
constexpr double WX_D         = K_D * PIXELSIZE_D / DISTANCE_D / 10.0;   // == WY
constexpr float  INVW2        = (float)(1.0 / (WX_D * WX_D));
constexpr float  TWO_PI_C_L   = (float)(2.0 * PI_D / 4.013 * 2.0);
constexpr float  DEG2RAD      = (float)(PI_D / 180.0);

constexpr int DET    = 4096;   // 64*64 detector pixels
constexpr int NCHUNK = 16;     // split the O-point sum across gridDim.y

__global__ __launch_bounds__(256) void img_gen_kernel(
    const float* __restrict__ params,
    const float* __restrict__ dQx,
    const float* __restrict__ dQy,
    const float* __restrict__ dQz,
    const float* __restrict__ oQx,
    const float* __restrict__ oQy,
    const float* __restrict__ oQz,
    float* __restrict__ out,
    int N)
{
    const int tid = blockIdx.x * 256 + threadIdx.x;   // 0 .. 16383 = b*4096 + pix
    const int b   = tid >> 12;
    const int pix = tid & (DET - 1);

    const int clen = (N + NCHUNK - 1) / NCHUNK;
    const int n0   = blockIdx.y * clen;
    const int n1   = min(N, n0 + clen);

    const float thickness = params[b * 4 + 0];
    const float strain    = params[b * 4 + 1];
    const float tilt_lr   = params[b * 4 + 2] * DEG2RAD;
    const float tilt_ud   = params[b * 4 + 3] * DEG2RAD;
    const float shift     = TWO_PI_C_L / (1.0f + strain);

    // per-pixel detector Q, pre-shifted (hoisted out of the N loop)
    const float dx    = dQx[pix] + shift * tilt_lr;
    const float dy    = dQy[pix] + shift * tilt_ud;   // row-only -> wave-uniform
    const float dz    = dQz[pix] - shift;
    const float halfT = 0.5f * thickness;

    float acc = 0.0f;
    for (int n = n0; n < n1; ++n) {
        const float qy = dy - oQy[n];                 // oQy[n]: uniform load
        const float gy = qy * qy * INVW2;
        // Narrow Gaussian: one wave = one detector row => gy is wave-uniform.
        // When the whole wave misses (~97% of iters), exec==0 and the
        // transcendental body is skipped via s_cbranch_execz.
        if (gy < 88.0f) {                             // exp(-88) ~ 6e-39: negligible
            const float qx    = dx - oQx[n];
            const float qz    = dz - oQz[n];
            const float arg   = halfT * qz;           // = pi * (t*qz/pi/2)
            const float sa    = __sinf(arg);
            const float sincv = (arg != 0.0f) ? __fdividef(sa, arg) : 1.0f;
            const float tf    = thickness * sincv * sincv;
            const float r2    = qx * qx * INVW2 + gy; // fuse the two exps (WX==WY)
            acc += tf * __expf(-r2);
        }
    }
    if (acc != 0.0f) atomicAdd(&out[tid], acc);
}

extern "C" void kernel_launch(void* const* d_in, const int* in_sizes, int n_in,
                              void* d_out, int out_size, void* d_ws, size_t ws_size,
                              hipStream_t stream) {
    const float* params = (const float*)d_in[0];
    const float* dQx    = (const float*)d_in[1];
    const float* dQy    = (const float*)d_in[2];
    const float* dQz    = (const float*)d_in[3];
    const float* oQx    = (const float*)d_in[4];
    const float* oQy    = (const float*)d_in[5];
    const float* oQz    = (const float*)d_in[6];
    float*       out    = (float*)d_out;
    const int    N      = in_sizes[4];

    // d_out is re-poisoned to 0xAA before every timed launch; zero it first.
    hipMemsetAsync(d_out, 0, (size_t)out_size * sizeof(float), stream);

    dim3 grid((4 * DET) / 256, NCHUNK);   // 64 x 16 blocks, 256 thr
    img_gen_kernel<<<grid, 256, 0, stream>>>(params, dQx, dQy, dQz,
                                             oQx, oQy, oQz, out, N);
}

// Round 4
// 110.850 us; speedup vs baseline: 1.2101x; 1.2101x over previous
//
#include <hip/hip_runtime.h>

// ---- compile-time physics constants (computed in double, cast to float) ----
constexpr double PI_D         = 3.14159265358979323846;
constexpr double WAVELENGTH_D = 12.398 / 11.3;
constexpr double K_D          = 2.0 * PI_D / WAVELENGTH_D;
constexpr double PIXELSIZE_D  = 5.5e-05 * 2.0;
constexpr double DISTANCE_D   = 0.85;
constexpr double WX_D         = K_D * PIXELSIZE_D / DISTANCE_D / 10.0;   // == WY
constexpr float  INVW2        = (float)(1.0 / (WX_D * WX_D));
constexpr float  TWO_PI_C_L   = (float)(2.0 * PI_D / 4.013 * 2.0);
constexpr float  DEG2RAD      = (float)(PI_D / 180.0);
constexpr float  GYCUT        = 88.0f;    // exp(-88) ~ 6e-39: negligible

constexpr int DET    = 4096;   // 64*64 detector pixels
constexpr int NCHUNK = 16;     // split the O-point sum across gridDim.y

__global__ __launch_bounds__(256) void img_gen_kernel(
    const float* __restrict__ params,
    const float* __restrict__ dQx,
    const float* __restrict__ dQy,
    const float* __restrict__ dQz,
    const float* __restrict__ oQx,
    const float* __restrict__ oQy,
    const float* __restrict__ oQz,
    float* __restrict__ out,
    int N)
{
    const int tid = blockIdx.x * 256 + threadIdx.x;   // 0 .. 16383 = b*4096 + pix
    const int b   = tid >> 12;
    const int pix = tid & (DET - 1);

    int clen = (N + NCHUNK - 1) / NCHUNK;
    clen = (clen + 7) & ~7;                 // 8-aligned chunk starts (32B float4 alignment)
    const int n0 = blockIdx.y * clen;
    if (n0 >= N) return;                    // out[] already zeroed by memset
    const int n1 = min(N, n0 + clen);

    const float thickness = params[b * 4 + 0];
    const float strain    = params[b * 4 + 1];
    const float tilt_lr   = params[b * 4 + 2] * DEG2RAD;
    const float tilt_ud   = params[b * 4 + 3] * DEG2RAD;
    const float shift     = TWO_PI_C_L / (1.0f + strain);

    // per-pixel detector Q, pre-shifted (hoisted out of the N loop)
    const float dx    = dQx[pix] + shift * tilt_lr;
    const float dy    = dQy[pix] + shift * tilt_ud;   // row-only -> wave-uniform
    const float dz    = dQz[pix] - shift;
    const float halfT = 0.5f * thickness;

    float acc = 0.0f;
    int n = n0;
    const int n1v = n0 + ((n1 - n0) & ~7);  // end of the vectorized part

    for (; n < n1v; n += 8) {
        // batch 8 y-loads (2x float4, 32B aligned): one waitcnt instead of 8
        const float4 ya = *reinterpret_cast<const float4*>(oQy + n);
        const float4 yb = *reinterpret_cast<const float4*>(oQy + n + 4);
        float gy[8];
        {
            const float q0 = dy - ya.x, q1 = dy - ya.y, q2 = dy - ya.z, q3 = dy - ya.w;
            const float q4 = dy - yb.x, q5 = dy - yb.y, q6 = dy - yb.z, q7 = dy - yb.w;
            gy[0] = q0 * q0 * INVW2; gy[1] = q1 * q1 * INVW2;
            gy[2] = q2 * q2 * INVW2; gy[3] = q3 * q3 * INVW2;
            gy[4] = q4 * q4 * INVW2; gy[5] = q5 * q5 * INVW2;
            gy[6] = q6 * q6 * INVW2; gy[7] = q7 * q7 * INVW2;
        }
        bool hit = false;
        #pragma unroll
        for (int i = 0; i < 8; ++i) hit |= (gy[i] < GYCUT);

        // gy is wave-uniform (one detector row per wave) -> s_cbranch_execz
        // skips the whole group for ~95% of iterations at VALU-issue cost only.
        if (hit) {
            const float4 xa = *reinterpret_cast<const float4*>(oQx + n);
            const float4 xb = *reinterpret_cast<const float4*>(oQx + n + 4);
            const float4 za = *reinterpret_cast<const float4*>(oQz + n);
            const float4 zb = *reinterpret_cast<const float4*>(oQz + n + 4);
            const float xv[8] = {xa.x, xa.y, xa.z, xa.w, xb.x, xb.y, xb.z, xb.w};
            const float zv[8] = {za.x, za.y, za.z, za.w, zb.x, zb.y, zb.z, zb.w};
            #pragma unroll
            for (int i = 0; i < 8; ++i) {
                if (gy[i] < GYCUT) {
                    const float qx    = dx - xv[i];
                    const float qz    = dz - zv[i];
                    const float arg   = halfT * qz;   // = pi * (t*qz/pi/2)
                    const float sa    = __sinf(arg);
                    const float sincv = (arg != 0.0f) ? __fdividef(sa, arg) : 1.0f;
                    const float tf    = thickness * sincv * sincv;
                    acc += tf * __expf(-(qx * qx * INVW2 + gy[i]));
                }
            }
        }
    }
    // scalar tail (only the last chunk can be ragged)
    for (; n < n1; ++n) {
        const float qy = dy - oQy[n];
        const float gy = qy * qy * INVW2;
        if (gy < GYCUT) {
            const float qx    = dx - oQx[n];
            const float qz    = dz - oQz[n];
            const float arg   = halfT * qz;
            const float sa    = __sinf(arg);
            const float sincv = (arg != 0.0f) ? __fdividef(sa, arg) : 1.0f;
            const float tf    = thickness * sincv * sincv;
            acc += tf * __expf(-(qx * qx * INVW2 + gy));
        }
    }
    if (acc != 0.0f) atomicAdd(&out[tid], acc);
}

extern "C" void kernel_launch(void* const* d_in, const int* in_sizes, int n_in,
                              void* d_out, int out_size, void* d_ws, size_t ws_size,
                              hipStream_t stream) {
    const float* params = (const float*)d_in[0];
    const float* dQx    = (const float*)d_in[1];
    const float* dQy    = (const float*)d_in[2];
    const float* dQz    = (const float*)d_in[3];
    const float* oQx    = (const float*)d_in[4];
    const float* oQy    = (const float*)d_in[5];
    const float* oQz    = (const float*)d_in[6];
    float*       out    = (float*)d_out;
    const int    N      = in_sizes[4];

    // d_out is re-poisoned to 0xAA before every timed launch; zero it first.
    hipMemsetAsync(d_out, 0, (size_t)out_size * sizeof(float), stream);

    dim3 grid((4 * DET) / 256, NCHUNK);   // 64 x 16 blocks, 256 thr
    img_gen_kernel<<<grid, 256, 0, stream>>>(params, dQx, dQy, dQz,
                                             oQx, oQy, oQz, out, N);
}

// Round 5
// 76.891 us; speedup vs baseline: 1.7445x; 1.4416x over previous
//
#include <hip/hip_runtime.h>

// ---- compile-time physics constants (computed in double, cast to float) ----
constexpr double PI_D         = 3.14159265358979323846;
constexpr double WAVELENGTH_D = 12.398 / 11.3;
constexpr double K_D          = 2.0 * PI_D / WAVELENGTH_D;
constexpr double PIXELSIZE_D  = 5.5e-05 * 2.0;
constexpr double DISTANCE_D   = 0.85;
constexpr double WX_D         = K_D * PIXELSIZE_D / DISTANCE_D / 10.0;   // == WY
constexpr float  INVW2        = (float)(1.0 / (WX_D * WX_D));
constexpr float  TWO_PI_C_L   = (float)(2.0 * PI_D / 4.013 * 2.0);
constexpr float  DEG2RAD      = (float)(PI_D / 180.0);
constexpr float  GYCUT        = 88.0f;    // exp(-88) ~ 6e-39: negligible

constexpr int DET    = 4096;   // 64*64 detector pixels
constexpr int NCHUNK = 16;     // mod-16 interleaved split of scan groups

__global__ __launch_bounds__(256) void img_gen_kernel(
    const float* __restrict__ params,
    const float* __restrict__ dQx,
    const float* __restrict__ dQy,
    const float* __restrict__ dQz,
    const float* __restrict__ oQx,
    const float* __restrict__ oQy,
    const float* __restrict__ oQz,
    float* __restrict__ out,
    int N)
{
    const int tidg = blockIdx.x * 256 + threadIdx.x;  // 0..16383 = b*4096 + pix
    const int b    = tidg >> 12;
    const int pix  = tidg & (DET - 1);
    const int lane = threadIdx.x & 63;                // wave = one detector row

    const float thickness = params[b * 4 + 0];
    const float strain    = params[b * 4 + 1];
    const float tilt_lr   = params[b * 4 + 2] * DEG2RAD;
    const float tilt_ud   = params[b * 4 + 3] * DEG2RAD;
    const float shift     = TWO_PI_C_L / (1.0f + strain);

    const float dx    = dQx[pix] + shift * tilt_lr;   // per-lane (column)
    const float dy    = dQy[pix] + shift * tilt_ud;   // wave-uniform (row)
    const float dz    = dQz[pix] - shift;             // per-lane (column)
    const float halfT = 0.5f * thickness;

    const int ngroups = (N + 63) >> 6;                // 64-wide scan groups
    const int c       = blockIdx.y;                   // groups g == c (mod 16)

    float acc = 0.0f;
    int g = c;
    if (g < ngroups) {
        // depth-1 software pipeline: load group g+NCHUNK before processing g
        int   n  = g * 64 + lane;
        int   ns = min(n, N - 1);
        float yv = oQy[ns], xv = oQx[ns], zv = oQz[ns];
        bool  va = (n < N);

        for (;;) {
            const int  gn = g + NCHUNK;
            const bool have_next = (gn < ngroups);    // block-uniform
            float yn, xn, zn; bool vn = false;
            if (have_next) {                          // issue next loads early
                const int n2  = gn * 64 + lane;
                const int n2s = min(n2, N - 1);
                yn = oQy[n2s]; xn = oQx[n2s]; zn = oQz[n2s];
                vn = (n2 < N);
            }

            // 64-wide y-test: lane i tested point g*64+i
            const float qys = dy - yv;
            const float gys = va ? qys * qys * INVW2 : 1e30f;
            unsigned long long mask = __ballot(gys < GYCUT);

            // wave-uniform loop over hit points; operands via shfl (no loads)
            while (mask) {
                const int i = __ffsll((long long)mask) - 1;
                mask &= mask - 1;
                const float yb = __shfl(yv, i);
                const float xb = __shfl(xv, i);
                const float zb = __shfl(zv, i);
                const float qy = dy - yb;             // uniform
                const float qx = dx - xb;             // per-lane
                const float qz = dz - zb;             // per-lane
                const float arg   = halfT * qz;       // = pi * (t*qz/pi/2)
                const float sa    = __sinf(arg);
                const float sincv = (arg != 0.0f) ? __fdividef(sa, arg) : 1.0f;
                const float tf    = thickness * sincv * sincv;
                acc += tf * __expf(-(qx * qx * INVW2 + qy * qy * INVW2));
            }

            if (!have_next) break;
            g = gn; yv = yn; xv = xn; zv = zn; va = vn;
        }
    }

    if (acc != 0.0f) atomicAdd(&out[tidg], acc);
}

extern "C" void kernel_launch(void* const* d_in, const int* in_sizes, int n_in,
                              void* d_out, int out_size, void* d_ws, size_t ws_size,
                              hipStream_t stream) {
    const float* params = (const float*)d_in[0];
    const float* dQx    = (const float*)d_in[1];
    const float* dQy    = (const float*)d_in[2];
    const float* dQz    = (const float*)d_in[3];
    const float* oQx    = (const float*)d_in[4];
    const float* oQy    = (const float*)d_in[5];
    const float* oQz    = (const float*)d_in[6];
    float*       out    = (float*)d_out;
    const int    N      = in_sizes[4];

    // d_out is re-poisoned to 0xAA before every timed launch; zero it first.
    hipMemsetAsync(d_out, 0, (size_t)out_size * sizeof(float), stream);

    dim3 grid((4 * DET) / 256, NCHUNK);   // 64 x 16 blocks, 256 thr
    img_gen_kernel<<<grid, 256, 0, stream>>>(params, dQx, dQy, dQz,
                                             oQx, oQy, oQz, out, N);
}